// Round 1
// baseline (214.273 us; speedup 1.0000x reference)
//
#include <hip/hip_runtime.h>

#define N_NODES 10000
#define N_EDGES 320000
#define OBS_DIM 30
#define ACT_DIM 4
#define HID 128

// ---------------- CSR build ----------------

__global__ void k_hist(const int* __restrict__ dst, int* __restrict__ cnt) {
    int e = blockIdx.x * blockDim.x + threadIdx.x;
    if (e < N_EDGES) atomicAdd(&cnt[dst[e]], 1);
}

// Single-block exclusive scan over cnt -> rowptr; also dis[i] = 1/sqrt(cnt[i]+1)
__global__ __launch_bounds__(256) void k_scan(const int* __restrict__ cnt,
                                              int* __restrict__ rowptr,
                                              float* __restrict__ dis) {
    __shared__ int s[256];
    int t = threadIdx.x;
    const int CH = 40;  // 256*40 = 10240 >= 10000
    int beg = t * CH;
    int end = min(beg + CH, N_NODES);
    int sum = 0;
    for (int i = beg; i < end; ++i) sum += cnt[i];
    s[t] = sum;
    __syncthreads();
    // Hillis-Steele inclusive scan over 256 partials
    for (int off = 1; off < 256; off <<= 1) {
        int v = (t >= off) ? s[t - off] : 0;
        __syncthreads();
        s[t] += v;
        __syncthreads();
    }
    int run = s[t] - sum;  // exclusive prefix for this chunk
    for (int i = beg; i < end; ++i) {
        rowptr[i] = run;
        int c = cnt[i];
        dis[i] = 1.0f / sqrtf((float)(c + 1));  // +1 for self-loop
        run += c;
    }
    if (t == 255) rowptr[N_NODES] = s[255];
}

__global__ void k_fill(const int* __restrict__ src, const int* __restrict__ dst,
                       const int* __restrict__ rowptr, int* __restrict__ fill,
                       int* __restrict__ col) {
    int e = blockIdx.x * blockDim.x + threadIdx.x;
    if (e < N_EDGES) {
        int d = dst[e];
        int p = atomicAdd(&fill[d], 1);
        col[rowptr[d] + p] = src[e];
    }
}

// ---------------- GEMM1: y = dis[i] * (concat(obs,act) @ W)  [10000x34 @ 34x128]

__global__ __launch_bounds__(256) void k_gemm1(const float* __restrict__ obs,
                                               const float* __restrict__ act,
                                               const float* __restrict__ W,
                                               const float* __restrict__ dis,
                                               float* __restrict__ y) {
    __shared__ float xs[16 * 34];
    __shared__ float ws[34 * 128];
    int t = threadIdx.x;
    int row0 = blockIdx.x * 16;  // 625 * 16 = 10000 exactly
    for (int i = t; i < 16 * 34; i += 256) {
        int r = i / 34, k = i % 34;
        int row = row0 + r;
        xs[i] = (k < OBS_DIM) ? obs[row * OBS_DIM + k]
                              : act[row * ACT_DIM + (k - OBS_DIM)];
    }
    for (int i = t; i < 34 * 128; i += 256) ws[i] = W[i];
    __syncthreads();
    int c = t & 127, half = t >> 7;
    float acc[8] = {0, 0, 0, 0, 0, 0, 0, 0};
    for (int k = 0; k < 34; ++k) {
        float wv = ws[k * 128 + c];
#pragma unroll
        for (int r = 0; r < 8; ++r) acc[r] += xs[(half * 8 + r) * 34 + k] * wv;
    }
#pragma unroll
    for (int r = 0; r < 8; ++r) {
        int row = row0 + half * 8 + r;
        y[row * HID + c] = dis[row] * acc[r];
    }
}

// ---------------- aggregation: out[i] = relu(dis[i]*(sum_{j in N(i)} y[j] + y[i]) + b)

__global__ __launch_bounds__(256) void k_agg(const float* __restrict__ y,
                                             const int* __restrict__ rowptr,
                                             const int* __restrict__ col,
                                             const float* __restrict__ dis,
                                             const float* __restrict__ bias,
                                             float* __restrict__ out) {
    int t = threadIdx.x;
    int wave = t >> 6, lane = t & 63;
    int node = blockIdx.x * 4 + wave;
    if (node >= N_NODES) return;
    int beg = rowptr[node], end = rowptr[node + 1];
    const float* yn = y + node * HID;
    float a0 = yn[lane];
    float a1 = yn[64 + lane];
    for (int e = beg; e < end; ++e) {
        int j = col[e];  // wave-uniform
        const float* yj = y + j * HID;
        a0 += yj[lane];
        a1 += yj[64 + lane];
    }
    float di = dis[node];
    float r0 = di * a0 + bias[lane];
    float r1 = di * a1 + bias[64 + lane];
    out[node * HID + lane] = fmaxf(r0, 0.0f);
    out[node * HID + 64 + lane] = fmaxf(r1, 0.0f);
}

// ---------------- GEMM128: y = dis[i] * (x @ W)  [10000x128 @ 128x128]

__global__ __launch_bounds__(256) void k_gemm128(const float* __restrict__ x,
                                                 const float* __restrict__ W,
                                                 const float* __restrict__ dis,
                                                 float* __restrict__ y) {
    __shared__ float xs[16 * 128];
    __shared__ float ws[32 * 128];
    int t = threadIdx.x;
    int row0 = blockIdx.x * 16;
    for (int i = t; i < 2048; i += 256) xs[i] = x[row0 * 128 + i];
    int c = t & 127, half = t >> 7;
    float acc[8] = {0, 0, 0, 0, 0, 0, 0, 0};
    for (int ch = 0; ch < 4; ++ch) {
        __syncthreads();
        for (int i = t; i < 4096; i += 256) ws[i] = W[ch * 4096 + i];
        __syncthreads();
        for (int k = 0; k < 32; ++k) {
            float wv = ws[k * 128 + c];
#pragma unroll
            for (int r = 0; r < 8; ++r)
                acc[r] += xs[(half * 8 + r) * 128 + ch * 32 + k] * wv;
        }
    }
#pragma unroll
    for (int r = 0; r < 8; ++r) {
        int row = row0 + half * 8 + r;
        y[row * 128 + c] = dis[row] * acc[r];
    }
}

// ---------------- fused heads: q = relu(x@Wa + Ba) @ wb + bb  (both heads)

__global__ __launch_bounds__(256) void k_heads(const float* __restrict__ x,
                                               const float* __restrict__ W1, const float* __restrict__ B1,
                                               const float* __restrict__ w1b, const float* __restrict__ b1b,
                                               const float* __restrict__ W2, const float* __restrict__ B2,
                                               const float* __restrict__ w2b, const float* __restrict__ b2b,
                                               float* __restrict__ q1, float* __restrict__ q2) {
    __shared__ float xs[16 * 128];
    __shared__ float w1s[32 * 128];
    __shared__ float w2s[32 * 128];
    __shared__ float part1[4][8];
    __shared__ float part2[4][8];
    int t = threadIdx.x;
    int row0 = blockIdx.x * 16;
    for (int i = t; i < 2048; i += 256) xs[i] = x[row0 * 128 + i];
    int c = t & 127, half = t >> 7;
    float a1[8] = {0, 0, 0, 0, 0, 0, 0, 0};
    float a2[8] = {0, 0, 0, 0, 0, 0, 0, 0};
    for (int ch = 0; ch < 4; ++ch) {
        __syncthreads();
        for (int i = t; i < 4096; i += 256) {
            w1s[i] = W1[ch * 4096 + i];
            w2s[i] = W2[ch * 4096 + i];
        }
        __syncthreads();
        for (int k = 0; k < 32; ++k) {
            float wv1 = w1s[k * 128 + c];
            float wv2 = w2s[k * 128 + c];
#pragma unroll
            for (int r = 0; r < 8; ++r) {
                float xv = xs[(half * 8 + r) * 128 + ch * 32 + k];
                a1[r] += xv * wv1;
                a2[r] += xv * wv2;
            }
        }
    }
    float bb1 = B1[c], bb2 = B2[c];
    float v1 = w1b[c], v2 = w2b[c];
    float s1[8], s2[8];
#pragma unroll
    for (int r = 0; r < 8; ++r) {
        float h1 = fmaxf(a1[r] + bb1, 0.0f);
        float h2 = fmaxf(a2[r] + bb2, 0.0f);
        s1[r] = h1 * v1;
        s2[r] = h2 * v2;
    }
    // reduce each s over the 64 lanes of this wave
#pragma unroll
    for (int off = 1; off < 64; off <<= 1) {
#pragma unroll
        for (int r = 0; r < 8; ++r) {
            s1[r] += __shfl_xor(s1[r], off);
            s2[r] += __shfl_xor(s2[r], off);
        }
    }
    int wave = t >> 6, lane = t & 63;
    if (lane == 0) {
#pragma unroll
        for (int r = 0; r < 8; ++r) {
            part1[wave][r] = s1[r];
            part2[wave][r] = s2[r];
        }
    }
    __syncthreads();
    if (t < 16) {
        int hf = t >> 3, r = t & 7;
        int row = row0 + hf * 8 + r;
        q1[row] = part1[hf * 2][r] + part1[hf * 2 + 1][r] + b1b[0];
        q2[row] = part2[hf * 2][r] + part2[hf * 2 + 1][r] + b2b[0];
    }
}

extern "C" void kernel_launch(void* const* d_in, const int* in_sizes, int n_in,
                              void* d_out, int out_size, void* d_ws, size_t ws_size,
                              hipStream_t stream) {
    (void)in_sizes; (void)n_in; (void)out_size; (void)ws_size;
    const float* obs  = (const float*)d_in[0];
    const float* act  = (const float*)d_in[1];
    const int*   ei   = (const int*)d_in[2];
    const int*   src  = ei;
    const int*   dst  = ei + N_EDGES;
    const float* w_g1 = (const float*)d_in[3];
    const float* b_g1 = (const float*)d_in[4];
    const float* w_g2 = (const float*)d_in[5];
    const float* b_g2 = (const float*)d_in[6];
    const float* w_q1a = (const float*)d_in[7];
    const float* b_q1a = (const float*)d_in[8];
    const float* w_q1b = (const float*)d_in[9];
    const float* b_q1b = (const float*)d_in[10];
    const float* w_q2a = (const float*)d_in[11];
    const float* b_q2a = (const float*)d_in[12];
    const float* w_q2b = (const float*)d_in[13];
    const float* b_q2b = (const float*)d_in[14];
    float* out = (float*)d_out;

    char* ws = (char*)d_ws;
    size_t off = 0;
    auto alloc = [&](size_t bytes) {
        void* p = ws + off;
        off = (off + bytes + 255) & ~(size_t)255;
        return p;
    };
    int*   cnt    = (int*)alloc(N_NODES * 4);
    int*   fill   = (int*)alloc(N_NODES * 4);
    int*   rowptr = (int*)alloc((N_NODES + 1) * 4);
    float* dis    = (float*)alloc(N_NODES * 4);
    int*   col    = (int*)alloc((size_t)N_EDGES * 4);
    float* buf0   = (float*)alloc((size_t)N_NODES * HID * 4);
    float* buf1   = (float*)alloc((size_t)N_NODES * HID * 4);

    hipMemsetAsync(cnt, 0, N_NODES * 4, stream);
    hipMemsetAsync(fill, 0, N_NODES * 4, stream);

    k_hist<<<(N_EDGES + 255) / 256, 256, 0, stream>>>(dst, cnt);
    k_scan<<<1, 256, 0, stream>>>(cnt, rowptr, dis);
    k_fill<<<(N_EDGES + 255) / 256, 256, 0, stream>>>(src, dst, rowptr, fill, col);

    k_gemm1<<<625, 256, 0, stream>>>(obs, act, w_g1, dis, buf0);
    k_agg<<<2500, 256, 0, stream>>>(buf0, rowptr, col, dis, b_g1, buf1);
    k_gemm128<<<625, 256, 0, stream>>>(buf1, w_g2, dis, buf0);
    k_agg<<<2500, 256, 0, stream>>>(buf0, rowptr, col, dis, b_g2, buf1);
    k_heads<<<625, 256, 0, stream>>>(buf1, w_q1a, b_q1a, w_q1b, b_q1b,
                                     w_q2a, b_q2a, w_q2b, b_q2b,
                                     out, out + N_NODES);
}

// Round 2
// 154.254 us; speedup vs baseline: 1.3891x; 1.3891x over previous
//
#include <hip/hip_runtime.h>

#define N_NODES 10000
#define N_EDGES 320000
#define OBS_DIM 30
#define ACT_DIM 4
#define HID 128

// ---------------- zero scratch (replaces 2x hipMemsetAsync @ 42us each) ----------------

__global__ __launch_bounds__(256) void k_zero(int* __restrict__ cnt, int* __restrict__ fill) {
    int i = blockIdx.x * blockDim.x + threadIdx.x;
    if (i < N_NODES) {
        cnt[i] = 0;
        fill[i] = 0;
    }
}

// ---------------- CSR build ----------------

__global__ void k_hist(const int* __restrict__ dst, int* __restrict__ cnt) {
    int e = blockIdx.x * blockDim.x + threadIdx.x;
    if (e < N_EDGES) atomicAdd(&cnt[dst[e]], 1);
}

// Single-block exclusive scan over cnt -> rowptr; also dis[i] = 1/sqrt(cnt[i]+1)
__global__ __launch_bounds__(256) void k_scan(const int* __restrict__ cnt,
                                              int* __restrict__ rowptr,
                                              float* __restrict__ dis) {
    __shared__ int s[256];
    int t = threadIdx.x;
    const int CH = 40;  // 250*40 = 10000 exactly; threads 250..255 idle
    int beg = t * CH;
    bool active = beg < N_NODES;
    int vals[CH];
    int sum = 0;
    if (active) {
        const int4* cp = (const int4*)(cnt + beg);
#pragma unroll
        for (int v = 0; v < CH / 4; ++v) {
            int4 q = cp[v];
            vals[4 * v + 0] = q.x;
            vals[4 * v + 1] = q.y;
            vals[4 * v + 2] = q.z;
            vals[4 * v + 3] = q.w;
        }
#pragma unroll
        for (int i = 0; i < CH; ++i) sum += vals[i];
    }
    s[t] = sum;
    __syncthreads();
    // Hillis-Steele inclusive scan over 256 partials
    for (int off = 1; off < 256; off <<= 1) {
        int v = (t >= off) ? s[t - off] : 0;
        __syncthreads();
        s[t] += v;
        __syncthreads();
    }
    if (active) {
        int run = s[t] - sum;  // exclusive prefix for this chunk
        int rp[CH];
        float dv[CH];
#pragma unroll
        for (int i = 0; i < CH; ++i) {
            rp[i] = run;
            int c = vals[i];
            dv[i] = rsqrtf((float)(c + 1));  // +1 for self-loop
            run += c;
        }
        int4* rpp = (int4*)(rowptr + beg);
        float4* dp = (float4*)(dis + beg);
#pragma unroll
        for (int v = 0; v < CH / 4; ++v) {
            rpp[v] = make_int4(rp[4 * v], rp[4 * v + 1], rp[4 * v + 2], rp[4 * v + 3]);
            dp[v] = make_float4(dv[4 * v], dv[4 * v + 1], dv[4 * v + 2], dv[4 * v + 3]);
        }
    }
    if (t == 255) rowptr[N_NODES] = s[255];
}

__global__ void k_fill(const int* __restrict__ src, const int* __restrict__ dst,
                       const int* __restrict__ rowptr, int* __restrict__ fill,
                       int* __restrict__ col) {
    int e = blockIdx.x * blockDim.x + threadIdx.x;
    if (e < N_EDGES) {
        int d = dst[e];
        int p = atomicAdd(&fill[d], 1);
        col[rowptr[d] + p] = src[e];
    }
}

// ---------------- GEMM1: y = dis[i] * (concat(obs,act) @ W)  [10000x34 @ 34x128]

__global__ __launch_bounds__(256) void k_gemm1(const float* __restrict__ obs,
                                               const float* __restrict__ act,
                                               const float* __restrict__ W,
                                               const float* __restrict__ dis,
                                               float* __restrict__ y) {
    __shared__ float xs[16 * 34];
    __shared__ float ws[34 * 128];
    int t = threadIdx.x;
    int row0 = blockIdx.x * 16;  // 625 * 16 = 10000 exactly
    for (int i = t; i < 16 * 34; i += 256) {
        int r = i / 34, k = i % 34;
        int row = row0 + r;
        xs[i] = (k < OBS_DIM) ? obs[row * OBS_DIM + k]
                              : act[row * ACT_DIM + (k - OBS_DIM)];
    }
    {
        float4* wsp = (float4*)ws;
        const float4* Wp = (const float4*)W;
        for (int i = t; i < 34 * 128 / 4; i += 256) wsp[i] = Wp[i];
    }
    __syncthreads();
    int c = t & 127, half = t >> 7;
    float acc[8] = {0, 0, 0, 0, 0, 0, 0, 0};
    for (int k = 0; k < 34; ++k) {
        float wv = ws[k * 128 + c];
#pragma unroll
        for (int r = 0; r < 8; ++r) acc[r] += xs[(half * 8 + r) * 34 + k] * wv;
    }
#pragma unroll
    for (int r = 0; r < 8; ++r) {
        int row = row0 + half * 8 + r;
        y[row * HID + c] = dis[row] * acc[r];
    }
}

// ---------------- aggregation: out[i] = relu(dis[i]*(sum_{j in N(i)} y[j] + y[i]) + b)

__global__ __launch_bounds__(256) void k_agg(const float2* __restrict__ y,
                                             const int* __restrict__ rowptr,
                                             const int* __restrict__ col,
                                             const float* __restrict__ dis,
                                             const float2* __restrict__ bias,
                                             float2* __restrict__ out) {
    int t = threadIdx.x;
    int wave = t >> 6, lane = t & 63;
    int node = blockIdx.x * 4 + wave;
    if (node >= N_NODES) return;
    int beg = rowptr[node], end = rowptr[node + 1];
    float2 a = y[node * 64 + lane];
    int e = beg;
    for (; e + 4 <= end; e += 4) {
        int j0 = col[e], j1 = col[e + 1], j2 = col[e + 2], j3 = col[e + 3];
        float2 v0 = y[j0 * 64 + lane];
        float2 v1 = y[j1 * 64 + lane];
        float2 v2 = y[j2 * 64 + lane];
        float2 v3 = y[j3 * 64 + lane];
        a.x += (v0.x + v1.x) + (v2.x + v3.x);
        a.y += (v0.y + v1.y) + (v2.y + v3.y);
    }
    for (; e < end; ++e) {
        float2 v = y[col[e] * 64 + lane];
        a.x += v.x;
        a.y += v.y;
    }
    float di = dis[node];
    float2 b = bias[lane];
    float2 r;
    r.x = fmaxf(di * a.x + b.x, 0.0f);
    r.y = fmaxf(di * a.y + b.y, 0.0f);
    out[node * 64 + lane] = r;
}

// ---------------- GEMM128: y = dis[i] * (x @ W)  [10000x128 @ 128x128]

__global__ __launch_bounds__(256) void k_gemm128(const float* __restrict__ x,
                                                 const float* __restrict__ W,
                                                 const float* __restrict__ dis,
                                                 float* __restrict__ y) {
    __shared__ float xs[16 * 128];
    __shared__ float ws[32 * 128];
    int t = threadIdx.x;
    int row0 = blockIdx.x * 16;
    {
        float4* xsp = (float4*)xs;
        const float4* xp = (const float4*)(x + row0 * 128);
        for (int i = t; i < 512; i += 256) xsp[i] = xp[i];
    }
    int c = t & 127, half = t >> 7;
    float acc[8] = {0, 0, 0, 0, 0, 0, 0, 0};
    for (int ch = 0; ch < 4; ++ch) {
        __syncthreads();
        {
            float4* wsp = (float4*)ws;
            const float4* Wp = (const float4*)(W + ch * 4096);
            for (int i = t; i < 1024; i += 256) wsp[i] = Wp[i];
        }
        __syncthreads();
        for (int k = 0; k < 32; ++k) {
            float wv = ws[k * 128 + c];
#pragma unroll
            for (int r = 0; r < 8; ++r)
                acc[r] += xs[(half * 8 + r) * 128 + ch * 32 + k] * wv;
        }
    }
#pragma unroll
    for (int r = 0; r < 8; ++r) {
        int row = row0 + half * 8 + r;
        y[row * 128 + c] = dis[row] * acc[r];
    }
}

// ---------------- fused heads: q = relu(x@Wa + Ba) @ wb + bb  (both heads)

__global__ __launch_bounds__(256) void k_heads(const float* __restrict__ x,
                                               const float* __restrict__ W1, const float* __restrict__ B1,
                                               const float* __restrict__ w1b, const float* __restrict__ b1b,
                                               const float* __restrict__ W2, const float* __restrict__ B2,
                                               const float* __restrict__ w2b, const float* __restrict__ b2b,
                                               float* __restrict__ q1, float* __restrict__ q2) {
    __shared__ float xs[16 * 128];
    __shared__ float w1s[32 * 128];
    __shared__ float w2s[32 * 128];
    __shared__ float part1[4][8];
    __shared__ float part2[4][8];
    int t = threadIdx.x;
    int row0 = blockIdx.x * 16;
    {
        float4* xsp = (float4*)xs;
        const float4* xp = (const float4*)(x + row0 * 128);
        for (int i = t; i < 512; i += 256) xsp[i] = xp[i];
    }
    int c = t & 127, half = t >> 7;
    float a1[8] = {0, 0, 0, 0, 0, 0, 0, 0};
    float a2[8] = {0, 0, 0, 0, 0, 0, 0, 0};
    for (int ch = 0; ch < 4; ++ch) {
        __syncthreads();
        {
            float4* w1p = (float4*)w1s;
            float4* w2p = (float4*)w2s;
            const float4* W1p = (const float4*)(W1 + ch * 4096);
            const float4* W2p = (const float4*)(W2 + ch * 4096);
            for (int i = t; i < 1024; i += 256) {
                w1p[i] = W1p[i];
                w2p[i] = W2p[i];
            }
        }
        __syncthreads();
        for (int k = 0; k < 32; ++k) {
            float wv1 = w1s[k * 128 + c];
            float wv2 = w2s[k * 128 + c];
#pragma unroll
            for (int r = 0; r < 8; ++r) {
                float xv = xs[(half * 8 + r) * 128 + ch * 32 + k];
                a1[r] += xv * wv1;
                a2[r] += xv * wv2;
            }
        }
    }
    float bb1 = B1[c], bb2 = B2[c];
    float v1 = w1b[c], v2 = w2b[c];
    float s1[8], s2[8];
#pragma unroll
    for (int r = 0; r < 8; ++r) {
        float h1 = fmaxf(a1[r] + bb1, 0.0f);
        float h2 = fmaxf(a2[r] + bb2, 0.0f);
        s1[r] = h1 * v1;
        s2[r] = h2 * v2;
    }
    // reduce each s over the 64 lanes of this wave
#pragma unroll
    for (int off = 1; off < 64; off <<= 1) {
#pragma unroll
        for (int r = 0; r < 8; ++r) {
            s1[r] += __shfl_xor(s1[r], off);
            s2[r] += __shfl_xor(s2[r], off);
        }
    }
    int wave = t >> 6, lane = t & 63;
    if (lane == 0) {
#pragma unroll
        for (int r = 0; r < 8; ++r) {
            part1[wave][r] = s1[r];
            part2[wave][r] = s2[r];
        }
    }
    __syncthreads();
    if (t < 16) {
        int hf = t >> 3, r = t & 7;
        int row = row0 + hf * 8 + r;
        q1[row] = part1[hf * 2][r] + part1[hf * 2 + 1][r] + b1b[0];
        q2[row] = part2[hf * 2][r] + part2[hf * 2 + 1][r] + b2b[0];
    }
}

extern "C" void kernel_launch(void* const* d_in, const int* in_sizes, int n_in,
                              void* d_out, int out_size, void* d_ws, size_t ws_size,
                              hipStream_t stream) {
    (void)in_sizes; (void)n_in; (void)out_size; (void)ws_size;
    const float* obs  = (const float*)d_in[0];
    const float* act  = (const float*)d_in[1];
    const int*   ei   = (const int*)d_in[2];
    const int*   src  = ei;
    const int*   dst  = ei + N_EDGES;
    const float* w_g1 = (const float*)d_in[3];
    const float* b_g1 = (const float*)d_in[4];
    const float* w_g2 = (const float*)d_in[5];
    const float* b_g2 = (const float*)d_in[6];
    const float* w_q1a = (const float*)d_in[7];
    const float* b_q1a = (const float*)d_in[8];
    const float* w_q1b = (const float*)d_in[9];
    const float* b_q1b = (const float*)d_in[10];
    const float* w_q2a = (const float*)d_in[11];
    const float* b_q2a = (const float*)d_in[12];
    const float* w_q2b = (const float*)d_in[13];
    const float* b_q2b = (const float*)d_in[14];
    float* out = (float*)d_out;

    char* ws = (char*)d_ws;
    size_t off = 0;
    auto alloc = [&](size_t bytes) {
        void* p = ws + off;
        off = (off + bytes + 255) & ~(size_t)255;
        return p;
    };
    int*   cnt    = (int*)alloc(N_NODES * 4);
    int*   fill   = (int*)alloc(N_NODES * 4);
    int*   rowptr = (int*)alloc((N_NODES + 1) * 4);
    float* dis    = (float*)alloc(N_NODES * 4);
    int*   col    = (int*)alloc((size_t)N_EDGES * 4);
    float* buf0   = (float*)alloc((size_t)N_NODES * HID * 4);
    float* buf1   = (float*)alloc((size_t)N_NODES * HID * 4);

    k_zero<<<(N_NODES + 255) / 256, 256, 0, stream>>>(cnt, fill);
    k_hist<<<(N_EDGES + 255) / 256, 256, 0, stream>>>(dst, cnt);
    k_scan<<<1, 256, 0, stream>>>(cnt, rowptr, dis);
    k_fill<<<(N_EDGES + 255) / 256, 256, 0, stream>>>(src, dst, rowptr, fill, col);

    k_gemm1<<<625, 256, 0, stream>>>(obs, act, w_g1, dis, buf0);
    k_agg<<<2500, 256, 0, stream>>>((const float2*)buf0, rowptr, col, dis,
                                    (const float2*)b_g1, (float2*)buf1);
    k_gemm128<<<625, 256, 0, stream>>>(buf1, w_g2, dis, buf0);
    k_agg<<<2500, 256, 0, stream>>>((const float2*)buf0, rowptr, col, dis,
                                    (const float2*)b_g2, (float2*)buf1);
    k_heads<<<625, 256, 0, stream>>>(buf1, w_q1a, b_q1a, w_q1b, b_q1b,
                                     w_q2a, b_q2a, w_q2b, b_q2b,
                                     out, out + N_NODES);
}